// Round 5
// baseline (264.959 us; speedup 1.0000x reference)
//
#include <hip/hip_runtime.h>

// [T+1, B] = [1024, 4096] fp32, time-major.
#define T      1023
#define B      4096
#define CHUNK  16
#define NCHUNK 64        // 64 chunks of 16 steps; t=1023 is an identity pad step
#define NCB    16        // column-blocks of 256 columns each
#define NBLK   (NCHUNK * NCB)   // 1024 blocks == 256 CUs x 4 blocks/CU (co-resident)

#define GAMMA     0.99f
#define TD_LAMBDA 0.95f

// Reset cross-block flags each call (d_ws is re-poisoned to 0xAA by the harness).
__global__ void k_zero(int* __restrict__ flags) { flags[threadIdx.x] = 0; }

// GAE step: adv[t] = nl_t*(delta_t + wd_t*adv[t+1]) == a_t + b_t*adv[t+1]
// loss[t] = (adv[t] + m_t)^2,  m_t = tv[t] - value[t]
// Single pass: compose chunk in regs -> publish aggregate -> lookback -> replay.
__global__ __launch_bounds__(256, 4) void k_gae(
    const float* __restrict__ value, const float* __restrict__ tv,
    const float* __restrict__ rew, const int* __restrict__ st,
    const float* __restrict__ disc,
    float* __restrict__ AggA, float* __restrict__ AggB,
    int* __restrict__ flags, float* __restrict__ out)
{
    const int bid = blockIdx.x;
    const int cb  = bid & (NCB - 1);
    // Reversed chunk order: earliest-dispatched blocks are the highest chunks,
    // which have no dependencies — safe progress even under partial residency.
    const int c   = (NCHUNK - 1) - (bid >> 4);
    const int col = cb * 256 + threadIdx.x;
    const int s   = c * CHUNK;

    float a[CHUNK], b[CHUNK], m[CHUNK];

    // ---- Phase 1: compose own chunk, inputs read ONCE into registers ----
    float A = 0.f, Bf = 1.f;
    float tvn = tv[min(s + CHUNK, T) * B + col];
    #pragma unroll
    for (int k = CHUNK - 1; k >= 0; --k) {
        const int t = s + k;
        if (t < T) {                          // false only for (c=63, k=15)
            const int i0 = t * B + col;
            const int i1 = i0 + B;
            const float d1    = disc[i1] * GAMMA;
            const float tvt   = tv[i0];
            const float delta = rew[i1] + d1 * tvn - tvt;
            const float nl    = (st[i0] == 2) ? 0.f : 1.f;
            a[k] = nl * delta;
            b[k] = nl * (d1 * TD_LAMBDA);
            m[k] = tvt - value[i0];
            A  = fmaf(b[k], A, a[k]);
            Bf *= b[k];
            tvn = tvt;
        } else { a[k] = 0.f; b[k] = 1.f; m[k] = 0.f; }   // identity pad
    }

    // ---- Phase 2: publish chunk aggregate, then release flag ----
    const int ag = c * B + col;
    AggA[ag] = A;
    AggB[ag] = Bf;
    __threadfence();                          // per-thread device-visibility
    __syncthreads();                          // all threads have fenced
    if (threadIdx.x == 0)
        __hip_atomic_store(&flags[c * NCB + cb], 1,
                           __ATOMIC_RELEASE, __HIP_MEMORY_SCOPE_AGENT);

    // ---- Phase 3: lane-parallel poll of all needed flags, then acquire ----
    const int num = (NCHUNK - 1) - c;         // chunks c+1 .. 63
    for (int i = threadIdx.x; i < num; i += 256) {
        const int f = (c + 1 + i) * NCB + cb;
        while (__hip_atomic_load(&flags[f], __ATOMIC_RELAXED,
                                 __HIP_MEMORY_SCOPE_AGENT) == 0) {}
    }
    __syncthreads();
    __builtin_amdgcn_fence(__ATOMIC_ACQUIRE, "agent");

    // Fold suffix aggregates (L2-hot), batched 8-wide to hide latency.
    float adv = 0.f;
    int cc = NCHUNK - 1;
    while (cc > c) {                          // wave-uniform trip count
        float Ab[8], Bb[8];
        #pragma unroll
        for (int k = 0; k < 8; ++k) {
            const int ccc = cc - k;
            const int i = (ccc > c ? ccc : cc) * B + col;
            Ab[k] = AggA[i];
            Bb[k] = AggB[i];
            if (ccc <= c) { Ab[k] = 0.f; Bb[k] = 1.f; }  // identity overrun
        }
        #pragma unroll
        for (int k = 0; k < 8; ++k)
            adv = fmaf(Bb[k], adv, Ab[k]);
        cc -= 8;
    }

    // ---- Phase 4: replay from registers; emit loss ----
    if (c == NCHUNK - 1)
        out[T * B + col] = 0.f;               // tensor_extend_zero row
    #pragma unroll
    for (int k = CHUNK - 1; k >= 0; --k) {
        adv = fmaf(b[k], adv, a[k]);          // pad step is a no-op (a=0,b=1)
        const int t = s + k;
        if (t < T) {
            const float td = adv + m[k];
            out[t * B + col] = td * td;
        }
    }
}

extern "C" void kernel_launch(void* const* d_in, const int* in_sizes, int n_in,
                              void* d_out, int out_size, void* d_ws, size_t ws_size,
                              hipStream_t stream) {
    // setup_inputs order: value, target_value, reward, step_type, discount
    const float* value = (const float*)d_in[0];
    const float* tv    = (const float*)d_in[1];
    const float* rew   = (const float*)d_in[2];
    const int*   st    = (const int*)d_in[3];
    const float* disc  = (const float*)d_in[4];
    float* out = (float*)d_out;

    float* AggA = (float*)d_ws;                       // [NCHUNK][B] — 1 MiB
    float* AggB = AggA + (size_t)NCHUNK * B;          // 1 MiB
    int*   flags = (int*)(AggB + (size_t)NCHUNK * B); // 1024 ints

    k_zero<<<1, NBLK, 0, stream>>>(flags);
    k_gae<<<NBLK, 256, 0, stream>>>(value, tv, rew, st, disc,
                                    AggA, AggB, flags, out);
}